// Round 14
// baseline (387.816 us; speedup 1.0000x reference)
//
#include <hip/hip_runtime.h>
#include <hip/hip_bf16.h>
#include <cstddef>
#include <cstdint>

// Problem constants (from reference)
#define NN 50000
#define MPAD 50048      // 391 tiles * 128
#define F_IN 128
#define NH 4
#define NC 64
#define NE 800000
#define NG 128
#define NOUT 8
#define HC 256          // NH*NC
#define EP (NE + NN)    // edges + self loops

typedef unsigned short ushort_t;
typedef _Float16 f16;
typedef __attribute__((ext_vector_type(2))) _Float16 f16x2;
typedef __attribute__((ext_vector_type(8))) _Float16 f16x8;
typedef __attribute__((ext_vector_type(4))) float f32x4;

// ---------------------------------------------------------------------------
// helpers
// ---------------------------------------------------------------------------
__device__ __forceinline__ float lrelu02(float x) { return x > 0.0f ? x : 0.2f * x; }
__device__ __forceinline__ float elu1(float x)    { return x > 0.0f ? x : expm1f(x); }

__device__ __forceinline__ ushort_t f2h_bits(float f) {
    f16 h = (f16)f;
    union { f16 h; ushort_t u; } cv; cv.h = h;
    return cv.u;
}
__device__ __forceinline__ uint32_t pack2h(float a, float b) {
    union { f16 h[2]; uint32_t u; } cv;
    cv.h[0] = (f16)a; cv.h[1] = (f16)b;
    return cv.u;
}
__device__ __forceinline__ f16x2 as_h2(uint32_t q) {
    union { uint32_t u; f16x2 h; } cv; cv.u = q;
    return cv.h;
}
__device__ __forceinline__ void h2_unpack(uint32_t q, float& lo, float& hi) {
    union { uint32_t u; f16 h[2]; } cv; cv.u = q;
    lo = (float)cv.h[0];
    hi = (float)cv.h[1];
}

// async global -> LDS, 16B per lane; lds dest = wave-uniform base + lane*16
__device__ __forceinline__ void gld16(const void* g, void* l) {
    __builtin_amdgcn_global_load_lds(
        (const __attribute__((address_space(1))) unsigned int*)g,
        (__attribute__((address_space(3))) unsigned int*)l, 16, 0, 0);
}

// ---------------------------------------------------------------------------
// fused prep: edge histogram + x->fp16 + W->fp16^T
// (NO batch histogram — 50K same-line float atomics cost 187us in R8.)
// ---------------------------------------------------------------------------
#define XN4 (NN * F_IN / 4)
#define NW (F_IN * HC + HC * HC)
__global__ void prep_kernel(const int* __restrict__ edst,
                            const float* __restrict__ x,
                            const float* __restrict__ W1,
                            const float* __restrict__ W2,
                            int* __restrict__ deg,
                            f16* __restrict__ xh,
                            f16* __restrict__ w1t, f16* __restrict__ w2t) {
    int idx = blockIdx.x * blockDim.x + threadIdx.x;
    if (idx < EP) {
        int d = (idx < NE) ? edst[idx] : (idx - NE);
        atomicAdd(&deg[d], 1);
        return;
    }
    idx -= EP;
    if (idx < XN4) {
        float4 v = ((const float4*)x)[idx];
        f16 o[4] = {(f16)v.x, (f16)v.y, (f16)v.z, (f16)v.w};
        *(uint2*)(xh + idx * 4) = *(const uint2*)o;
        return;
    }
    idx -= XN4;
    const int n1 = F_IN * HC;
    if (idx < n1) {
        int k = idx / HC, n = idx % HC;
        w1t[n * F_IN + k] = (f16)W1[idx];
    } else if (idx < NW) {
        int i2 = idx - n1;
        int k = i2 / HC, n = i2 % HC;
        w2t[n * HC + k] = (f16)W2[i2];
    }
}

// ---------------------------------------------------------------------------
// CSR build: exclusive scan + fill (src ids, dst-sorted)
// ---------------------------------------------------------------------------
__global__ __launch_bounds__(256) void scan_p1(const int* __restrict__ deg,
                                               int* __restrict__ partials) {
    __shared__ int lds[256];
    int b = blockIdx.x, t = threadIdx.x;
    int i0 = b * 1024 + t * 4;
    int s = 0;
#pragma unroll
    for (int j = 0; j < 4; j++) { int i = i0 + j; if (i < NN) s += deg[i]; }
    lds[t] = s;
    __syncthreads();
    for (int o = 128; o; o >>= 1) { if (t < o) lds[t] += lds[t + o]; __syncthreads(); }
    if (t == 0) partials[b] = lds[0];
}

__global__ __launch_bounds__(256) void scan_p3(const int* __restrict__ deg,
                                               const int* __restrict__ partials,
                                               int* __restrict__ offs) {
    __shared__ int lds[256];
    __shared__ int base_s;
    int b = blockIdx.x, t = threadIdx.x;
    if (t == 0) {
        int s = 0;
        for (int i = 0; i < b; i++) s += partials[i];
        base_s = s;
        if (b == 0) offs[0] = 0;
    }
    int i0 = b * 1024 + t * 4;
    int v[4]; int s = 0;
#pragma unroll
    for (int j = 0; j < 4; j++) { int i = i0 + j; v[j] = (i < NN) ? deg[i] : 0; s += v[j]; }
    lds[t] = s;
    __syncthreads();
    for (int o = 1; o < 256; o <<= 1) {
        int x = (t >= o) ? lds[t - o] : 0;
        __syncthreads();
        lds[t] += x;
        __syncthreads();
    }
    int run = base_s + (lds[t] - s);
#pragma unroll
    for (int j = 0; j < 4; j++) { run += v[j]; int i = i0 + j; if (i < NN) offs[i + 1] = run; }
}

__global__ void edge_fill(const int* __restrict__ esrc, const int* __restrict__ edst,
                          const int* __restrict__ offs, int* __restrict__ fill,
                          int* __restrict__ csr) {
    int e = blockIdx.x * blockDim.x + threadIdx.x;
    if (e >= EP) return;
    int s, d;
    if (e < NE) { s = esrc[e]; d = edst[e]; } else { s = d = e - NE; }
    int pos = offs[d] + atomicAdd(&fill[d], 1);
    csr[pos] = s;
}

// ---------------------------------------------------------------------------
// fp16 MFMA GEMM, fused GAT epilogue (R10 shape, BK=32).
// C/D: col=lane&15, row=quad*4+reg. launch_bounds(256,3): 3 blocks/CU covers
// the per-iteration vmcnt(0) barrier drain (K-loop is only 4-8 iterations).
// hf2 dword layout [node][by*64+c]: dword = (hi: head 2by+1, lo: head 2by)
// packed fp16 for channel c (contiguous 256B/row per block).
// ---------------------------------------------------------------------------
__global__ __launch_bounds__(256, 3) void gemm_gat(
        const f16* __restrict__ A, const f16* __restrict__ BT,
        const float* __restrict__ a_s, const float* __restrict__ a_d,
        ushort_t* __restrict__ hf2, float* __restrict__ asrc,
        float* __restrict__ adst, int M, int K) {
    __shared__ alignas(16) char smem[33792];   // staging 16KB / repack 33.8KB
    f16* lA = (f16*)smem;            // [128 rows][32 k]
    f16* lB = (f16*)smem + 4096;     // [128 rows][32 k]

    int t = threadIdx.x;
    int wave = t >> 6, lane = t & 63;
    int wm = wave >> 1, wn = wave & 1;
    int quad = lane >> 4, l15 = lane & 15;
    int tileM = blockIdx.x * 128;
    int by = blockIdx.y;

    f32x4 acc[4][4];
#pragma unroll
    for (int f = 0; f < 4; f++)
#pragma unroll
        for (int g = 0; g < 4; g++) acc[f][g] = (f32x4){0.f, 0.f, 0.f, 0.f};

    for (int k0 = 0; k0 < K; k0 += 32) {
        __syncthreads();
#pragma unroll
        for (int i = 0; i < 2; i++) {
            int c = wave * 2 + i;
            int row = c * 16 + (lane >> 2);
            int kk = k0 + (lane & 3) * 8;
            gld16(A + (size_t)(tileM + row) * K + kk, &lA[c * 512]);
            gld16(BT + (size_t)(by * 128 + row) * K + kk, &lB[c * 512]);
        }
        __syncthreads();

        f16x8 ah[4], bh[4];
#pragma unroll
        for (int f = 0; f < 4; f++)
            ah[f] = *(const f16x8*)&lA[(wm * 64 + f * 16 + l15) * 32 + quad * 8];
#pragma unroll
        for (int g = 0; g < 4; g++)
            bh[g] = *(const f16x8*)&lB[(wn * 64 + g * 16 + l15) * 32 + quad * 8];
#pragma unroll
        for (int f = 0; f < 4; f++)
#pragma unroll
            for (int g = 0; g < 4; g++)
                acc[f][g] = __builtin_amdgcn_mfma_f32_16x16x32_f16(ah[f], bh[g], acc[f][g], 0, 0, 0);
    }

    // ---- epilogue 1: per-head attention dots (this wave's 64 cols = 1 head)
    int head = (by << 1) | wn;
    float as_v[4], ad_v[4];
#pragma unroll
    for (int g = 0; g < 4; g++) {
        as_v[g] = a_s[head * 64 + g * 16 + l15];
        ad_v[g] = a_d[head * 64 + g * 16 + l15];
    }
#pragma unroll
    for (int f = 0; f < 4; f++) {
#pragma unroll
        for (int r = 0; r < 4; r++) {
            float ps = acc[f][0][r] * as_v[0] + acc[f][1][r] * as_v[1]
                     + acc[f][2][r] * as_v[2] + acc[f][3][r] * as_v[3];
            float pd = acc[f][0][r] * ad_v[0] + acc[f][1][r] * ad_v[1]
                     + acc[f][2][r] * ad_v[2] + acc[f][3][r] * ad_v[3];
#pragma unroll
            for (int o = 1; o < 16; o <<= 1) {
                ps += __shfl_xor(ps, o);
                pd += __shfl_xor(pd, o);
            }
            int row = tileM + wm * 64 + f * 16 + quad * 4 + r;
            if (l15 == 0 && row < M) {
                asrc[row * 4 + head] = ps;
                adst[row * 4 + head] = pd;
            }
        }
    }

    // ---- epilogue 2: packed fp16 tile via padded LDS repack.
    // lC2 ushort layout: [128 rows][stride 132] ; ushort idx = c*2 + wn.
    __syncthreads();   // K-loop staging LDS dead
    ushort_t* lC2u = (ushort_t*)smem;
    const uint32_t* lC2d = (const uint32_t*)smem;
#pragma unroll
    for (int f = 0; f < 4; f++)
#pragma unroll
        for (int g = 0; g < 4; g++)
#pragma unroll
            for (int r = 0; r < 4; r++)
                lC2u[(wm * 64 + f * 16 + quad * 4 + r) * 132 + (g * 16 + l15) * 2 + wn] =
                    f2h_bits(acc[f][g][r]);
    __syncthreads();
    uint32_t* hb2 = (uint32_t*)hf2;
#pragma unroll
    for (int it = 0; it < 32; it++) {
        int row = wave * 32 + it;
        uint32_t v = lC2d[row * 66 + lane];
        hb2[(size_t)(tileM + row) * 128 + by * 64 + lane] = v;
    }
}

// ---------------------------------------------------------------------------
// GAT aggregation: one wave per node. Block = 4 waves = 4 nodes.
// deg<=64 fast path: plain softmax (logits 1/lane, 1 exp/head).
// Pass 2: manual 8-WIDE load batching with NAMED registers q0..q7 (static
// indices — arrays get demoted to LDS, named vars cannot be). R13's 4-wide
// proved latency-bound: 86->73us. 8-wide doubles rows in flight again.
// NT loads reverted (R12). CONCAT=1: fp16 act out; CONCAT=0: head-pair
// combine via shfl_xor(32) -> fp32 mean + bias.
// ---------------------------------------------------------------------------
template <int CONCAT>
__global__ __launch_bounds__(256) void gat_agg(const ushort_t* __restrict__ hf2,
                                               const float* __restrict__ asrc,
                                               const float* __restrict__ adst,
                                               const int* __restrict__ offs,
                                               const int* __restrict__ csr,
                                               const float* __restrict__ bias,
                                               f16* __restrict__ oh,
                                               float* __restrict__ of) {
    __shared__ uint2 lw[4][64];   // per-edge weights, packed (h_even,h_odd) fp16
    int wave = threadIdx.x >> 6, lane = threadIdx.x & 63;
    int node = blockIdx.x * 4 + wave;
    if (node >= NN) return;
    int start = offs[node];
    int deg = offs[node + 1] - start;
    float4 ad = *(const float4*)(adst + node * 4);

    float w0, w1, w2, w3;
    float m0, m1, m2, m3, i0, i1, i2, i3;
    int msrc = 0;

    if (deg <= 64) {
        // ---------- fast path: plain softmax, 1 exp/head ----------
        float t0 = -1e30f, t1 = -1e30f, t2 = -1e30f, t3 = -1e30f;
        if (lane < deg) {
            int sidx = csr[start + lane];
            float4 as = *(const float4*)(asrc + sidx * 4);
            t0 = lrelu02(as.x + ad.x);
            t1 = lrelu02(as.y + ad.y);
            t2 = lrelu02(as.z + ad.z);
            t3 = lrelu02(as.w + ad.w);
            msrc = sidx;
        }
        m0 = t0; m1 = t1; m2 = t2; m3 = t3;
#pragma unroll
        for (int o = 1; o < 64; o <<= 1) {
            m0 = fmaxf(m0, __shfl_xor(m0, o));
            m1 = fmaxf(m1, __shfl_xor(m1, o));
            m2 = fmaxf(m2, __shfl_xor(m2, o));
            m3 = fmaxf(m3, __shfl_xor(m3, o));
        }
        w0 = __expf(t0 - m0);
        w1 = __expf(t1 - m1);
        w2 = __expf(t2 - m2);
        w3 = __expf(t3 - m3);
        float s0 = w0, s1 = w1, s2 = w2, s3 = w3;
#pragma unroll
        for (int o = 1; o < 64; o <<= 1) {
            s0 += __shfl_xor(s0, o);
            s1 += __shfl_xor(s1, o);
            s2 += __shfl_xor(s2, o);
            s3 += __shfl_xor(s3, o);
        }
        i0 = 1.0f / (s0 + 1e-16f);
        i1 = 1.0f / (s1 + 1e-16f);
        i2 = 1.0f / (s2 + 1e-16f);
        i3 = 1.0f / (s3 + 1e-16f);
        w0 *= i0; w1 *= i1; w2 *= i2; w3 *= i3;
    } else {
        // ---------- slow path (deg>64; not hit for this input) ----------
        m0 = m1 = m2 = m3 = -1e30f;
        float s0 = 0.f, s1 = 0.f, s2 = 0.f, s3 = 0.f;
        float e0 = 0.f, e1 = 0.f, e2 = 0.f, e3 = 0.f;
        for (int j = lane; j < deg; j += 64) {
            int sidx = csr[start + j];
            float4 as = *(const float4*)(asrc + sidx * 4);
            float t0 = lrelu02(as.x + ad.x);
            float t1 = lrelu02(as.y + ad.y);
            float t2 = lrelu02(as.z + ad.z);
            float t3 = lrelu02(as.w + ad.w);
            if (j == lane) { e0 = t0; e1 = t1; e2 = t2; e3 = t3; msrc = sidx; }
            float nm;
            nm = fmaxf(m0, t0); s0 = s0 * __expf(m0 - nm) + __expf(t0 - nm); m0 = nm;
            nm = fmaxf(m1, t1); s1 = s1 * __expf(m1 - nm) + __expf(t1 - nm); m1 = nm;
            nm = fmaxf(m2, t2); s2 = s2 * __expf(m2 - nm) + __expf(t2 - nm); m2 = nm;
            nm = fmaxf(m3, t3); s3 = s3 * __expf(m3 - nm) + __expf(t3 - nm); m3 = nm;
        }
        for (int o = 32; o; o >>= 1) {
            float om, os, nm;
            om = __shfl_xor(m0, o); os = __shfl_xor(s0, o);
            nm = fmaxf(m0, om); s0 = s0 * __expf(m0 - nm) + os * __expf(om - nm); m0 = nm;
            om = __shfl_xor(m1, o); os = __shfl_xor(s1, o);
            nm = fmaxf(m1, om); s1 = s1 * __expf(m1 - nm) + os * __expf(om - nm); m1 = nm;
            om = __shfl_xor(m2, o); os = __shfl_xor(s2, o);
            nm = fmaxf(m2, om); s2 = s2 * __expf(m2 - nm) + os * __expf(om - nm); m2 = nm;
            om = __shfl_xor(m3, o); os = __shfl_xor(s3, o);
            nm = fmaxf(m3, om); s3 = s3 * __expf(m3 - nm) + os * __expf(om - nm); m3 = nm;
        }
        i0 = 1.0f / (s0 + 1e-16f);
        i1 = 1.0f / (s1 + 1e-16f);
        i2 = 1.0f / (s2 + 1e-16f);
        i3 = 1.0f / (s3 + 1e-16f);
        w0 = __expf(e0 - m0) * i0;
        w1 = __expf(e1 - m1) * i1;
        w2 = __expf(e2 - m2) * i2;
        w3 = __expf(e3 - m3) * i3;
    }

    // park weights in LDS, packed fp16 (wave-private; no barrier needed):
    // dword 0 = (w_head0, w_head1), dword 1 = (w_head2, w_head3)
    lw[wave][lane] = (uint2){pack2h(w0, w1), pack2h(w2, w3)};

    // gather: lane l -> head pair hp=l>>5, channels c0=2*(l&31), c0+1
    int hp = lane >> 5;
    const uint32_t* lwu = (const uint32_t*)&lw[wave][0];  // [64][2] dword view
    float aE0 = 0.f, aO0 = 0.f, aE1 = 0.f, aO1 = 0.f; // (even/odd head) x (c0/c1)
    const uint32_t* hb = (const uint32_t*)hf2 + lane * 2;
    int jmax = deg < 64 ? deg : 64;

    int j = 0;
    for (; j + 8 <= jmax; j += 8) {
        int s0 = __builtin_amdgcn_readlane(msrc, j);
        int s1 = __builtin_amdgcn_readlane(msrc, j + 1);
        int s2 = __builtin_amdgcn_readlane(msrc, j + 2);
        int s3 = __builtin_amdgcn_readlane(msrc, j + 3);
        int s4 = __builtin_amdgcn_readlane(msrc, j + 4);
        int s5 = __builtin_amdgcn_readlane(msrc, j + 5);
        int s6 = __builtin_amdgcn_readlane(msrc, j + 6);
        int s7 = __builtin_amdgcn_readlane(msrc, j + 7);
        uint2 q0 = *(const uint2*)(hb + (size_t)s0 * 128);
        uint2 q1 = *(const uint2*)(hb + (size_t)s1 * 128);
        uint2 q2 = *(const uint2*)(hb + (size_t)s2 * 128);
        uint2 q3 = *(const uint2*)(hb + (size_t)s3 * 128);
        uint2 q4 = *(const uint2*)(hb + (size_t)s4 * 128);
        uint2 q5 = *(const uint2*)(hb + (size_t)s5 * 128);
        uint2 q6 = *(const uint2*)(hb + (size_t)s6 * 128);
        uint2 q7 = *(const uint2*)(hb + (size_t)s7 * 128);
        f16x2 wA = as_h2(lwu[(j + 0) * 2 + hp]);
        f16x2 wB = as_h2(lwu[(j + 1) * 2 + hp]);
        f16x2 wC = as_h2(lwu[(j + 2) * 2 + hp]);
        f16x2 wD = as_h2(lwu[(j + 3) * 2 + hp]);
        f16x2 wE = as_h2(lwu[(j + 4) * 2 + hp]);
        f16x2 wF = as_h2(lwu[(j + 5) * 2 + hp]);
        f16x2 wG = as_h2(lwu[(j + 6) * 2 + hp]);
        f16x2 wH = as_h2(lwu[(j + 7) * 2 + hp]);
        f16x2 x0 = as_h2(q0.x), y0 = as_h2(q0.y);
        f16x2 x1 = as_h2(q1.x), y1 = as_h2(q1.y);
        f16x2 x2 = as_h2(q2.x), y2 = as_h2(q2.y);
        f16x2 x3 = as_h2(q3.x), y3 = as_h2(q3.y);
        f16x2 x4 = as_h2(q4.x), y4 = as_h2(q4.y);
        f16x2 x5 = as_h2(q5.x), y5 = as_h2(q5.y);
        f16x2 x6 = as_h2(q6.x), y6 = as_h2(q6.y);
        f16x2 x7 = as_h2(q7.x), y7 = as_h2(q7.y);
        aE0 += (float)x0[0] * (float)wA[0]; aO0 += (float)x0[1] * (float)wA[1];
        aE1 += (float)y0[0] * (float)wA[0]; aO1 += (float)y0[1] * (float)wA[1];
        aE0 += (float)x1[0] * (float)wB[0]; aO0 += (float)x1[1] * (float)wB[1];
        aE1 += (float)y1[0] * (float)wB[0]; aO1 += (float)y1[1] * (float)wB[1];
        aE0 += (float)x2[0] * (float)wC[0]; aO0 += (float)x2[1] * (float)wC[1];
        aE1 += (float)y2[0] * (float)wC[0]; aO1 += (float)y2[1] * (float)wC[1];
        aE0 += (float)x3[0] * (float)wD[0]; aO0 += (float)x3[1] * (float)wD[1];
        aE1 += (float)y3[0] * (float)wD[0]; aO1 += (float)y3[1] * (float)wD[1];
        aE0 += (float)x4[0] * (float)wE[0]; aO0 += (float)x4[1] * (float)wE[1];
        aE1 += (float)y4[0] * (float)wE[0]; aO1 += (float)y4[1] * (float)wE[1];
        aE0 += (float)x5[0] * (float)wF[0]; aO0 += (float)x5[1] * (float)wF[1];
        aE1 += (float)y5[0] * (float)wF[0]; aO1 += (float)y5[1] * (float)wF[1];
        aE0 += (float)x6[0] * (float)wG[0]; aO0 += (float)x6[1] * (float)wG[1];
        aE1 += (float)y6[0] * (float)wG[0]; aO1 += (float)y6[1] * (float)wG[1];
        aE0 += (float)x7[0] * (float)wH[0]; aO0 += (float)x7[1] * (float)wH[1];
        aE1 += (float)y7[0] * (float)wH[0]; aO1 += (float)y7[1] * (float)wH[1];
    }
    for (; j + 4 <= jmax; j += 4) {
        int s0 = __builtin_amdgcn_readlane(msrc, j);
        int s1 = __builtin_amdgcn_readlane(msrc, j + 1);
        int s2 = __builtin_amdgcn_readlane(msrc, j + 2);
        int s3 = __builtin_amdgcn_readlane(msrc, j + 3);
        uint2 q0 = *(const uint2*)(hb + (size_t)s0 * 128);
        uint2 q1 = *(const uint2*)(hb + (size_t)s1 * 128);
        uint2 q2 = *(const uint2*)(hb + (size_t)s2 * 128);
        uint2 q3 = *(const uint2*)(hb + (size_t)s3 * 128);
        f16x2 wA = as_h2(lwu[(j + 0) * 2 + hp]);
        f16x2 wB = as_h2(lwu[(j + 1) * 2 + hp]);
        f16x2 wC = as_h2(lwu[(j + 2) * 2 + hp]);
        f16x2 wD = as_h2(lwu[(j + 3) * 2 + hp]);
        f16x2 x0 = as_h2(q0.x), y0 = as_h2(q0.y);
        f16x2 x1 = as_h2(q1.x), y1 = as_h2(q1.y);
        f16x2 x2 = as_h2(q2.x), y2 = as_h2(q2.y);
        f16x2 x3 = as_h2(q3.x), y3 = as_h2(q3.y);
        aE0 += (float)x0[0] * (float)wA[0]; aO0 += (float)x0[1] * (float)wA[1];
        aE1 += (float)y0[0] * (float)wA[0]; aO1 += (float)y0[1] * (float)wA[1];
        aE0 += (float)x1[0] * (float)wB[0]; aO0 += (float)x1[1] * (float)wB[1];
        aE1 += (float)y1[0] * (float)wB[0]; aO1 += (float)y1[1] * (float)wB[1];
        aE0 += (float)x2[0] * (float)wC[0]; aO0 += (float)x2[1] * (float)wC[1];
        aE1 += (float)y2[0] * (float)wC[0]; aO1 += (float)y2[1] * (float)wC[1];
        aE0 += (float)x3[0] * (float)wD[0]; aO0 += (float)x3[1] * (float)wD[1];
        aE1 += (float)y3[0] * (float)wD[0]; aO1 += (float)y3[1] * (float)wD[1];
    }
    for (; j < jmax; j++) {
        int sidx = __builtin_amdgcn_readlane(msrc, j);
        f16x2 wh = as_h2(lwu[j * 2 + hp]);
        uint2 q = *(const uint2*)(hb + (size_t)sidx * 128);
        f16x2 qx = as_h2(q.x), qy = as_h2(q.y);
        aE0 += (float)qx[0] * (float)wh[0];
        aO0 += (float)qx[1] * (float)wh[1];
        aE1 += (float)qy[0] * (float)wh[0];
        aO1 += (float)qy[1] * (float)wh[1];
    }
    for (int jj = 64; jj < deg; jj++) {  // correctness fallback (deg>64); not hit
        int sidx = csr[start + jj];
        float4 as = *(const float4*)(asrc + sidx * 4);
        float u0 = __expf(lrelu02(as.x + ad.x) - m0) * i0;
        float u1 = __expf(lrelu02(as.y + ad.y) - m1) * i1;
        float u2 = __expf(lrelu02(as.z + ad.z) - m2) * i2;
        float u3 = __expf(lrelu02(as.w + ad.w) - m3) * i3;
        float ue = hp ? u2 : u0;
        float uo = hp ? u3 : u1;
        uint2 q = *(const uint2*)(hb + (size_t)sidx * 128);
        float xl, xh2, yl, yh;
        h2_unpack(q.x, xl, xh2);
        h2_unpack(q.y, yl, yh);
        aE0 += ue * xl;
        aO0 += uo * xh2;
        aE1 += ue * yl;
        aO1 += uo * yh;
    }

    int c0 = (lane & 31) * 2;
    int he = hp * 2, ho = hp * 2 + 1;
    if (CONCAT) {
        size_t base = (size_t)node * HC;
        float vE0 = elu1(aE0 + bias[he * 64 + c0]);
        float vE1 = elu1(aE1 + bias[he * 64 + c0 + 1]);
        float vO0 = elu1(aO0 + bias[ho * 64 + c0]);
        float vO1 = elu1(aO1 + bias[ho * 64 + c0 + 1]);
        f16 pe[2] = {(f16)vE0, (f16)vE1};
        f16 po[2] = {(f16)vO0, (f16)vO1};
        *(uint32_t*)(oh + base + he * 64 + c0) = *(const uint32_t*)pe;
        *(uint32_t*)(oh + base + ho * 64 + c0) = *(const uint32_t*)po;
    } else {
        float s0 = aE0 + aO0;     // pair-sum, channel c0
        float s1 = aE1 + aO1;     // pair-sum, channel c0+1
        s0 += __shfl_xor(s0, 32); // + other head pair
        s1 += __shfl_xor(s1, 32);
        if (hp == 0) {
            float2 v = {0.25f * s0 + bias[c0], 0.25f * s1 + bias[c0 + 1]};
            *(float2*)(of + (size_t)node * NC + c0) = v;
        }
    }
}

// ---------------------------------------------------------------------------
// global mean pool (batch sorted): run-length accumulate 16 nodes/wave,
// one atomic per (graph-run, wave) — FEW spread atomics, not a histogram.
// ---------------------------------------------------------------------------
__global__ __launch_bounds__(256) void pool_kernel(const float* __restrict__ out2,
                                                   const int* __restrict__ batch,
                                                   float* __restrict__ pool,
                                                   float* __restrict__ cnt) {
    int gw = (blockIdx.x * blockDim.x + threadIdx.x) >> 6;
    int lane = threadIdx.x & 63;
    int start = gw * 16;
    if (start >= NN) return;
    int end = start + 16 < NN ? start + 16 : NN;
    int curg = batch[start];
    float acc = 0.f; int run = 0;
    for (int node = start; node < end; node++) {
        int g = batch[node];
        if (g != curg) {
            atomicAdd(&pool[curg * 64 + lane], acc);
            if (lane == 0) atomicAdd(&cnt[curg], (float)run);
            curg = g; acc = 0.f; run = 0;
        }
        acc += out2[(size_t)node * NC + lane];
        run++;
    }
    atomicAdd(&pool[curg * 64 + lane], acc);
    if (lane == 0) atomicAdd(&cnt[curg], (float)run);
}

__global__ void fc_kernel(const float* __restrict__ pool, const float* __restrict__ cnt,
                          const float* __restrict__ fc_w, const float* __restrict__ fc_b,
                          float* __restrict__ out) {
    int idx = blockIdx.x * blockDim.x + threadIdx.x;
    if (idx >= NG * NOUT) return;
    int g = idx >> 3, o = idx & 7;
    float inv = 1.0f / fmaxf(cnt[g], 1.0f);
    float s = 0.f;
#pragma unroll
    for (int c = 0; c < 64; c++) s += pool[g * 64 + c] * fc_w[c * 8 + o];
    out[idx] = s * inv + fc_b[o];
}

// ---------------------------------------------------------------------------
extern "C" void kernel_launch(void* const* d_in, const int* in_sizes, int n_in,
                              void* d_out, int out_size, void* d_ws, size_t ws_size,
                              hipStream_t stream) {
    const float* x    = (const float*)d_in[0];
    const int*   ei   = (const int*)d_in[1];   // [2, E]
    const int*   batch= (const int*)d_in[2];
    const float* W1   = (const float*)d_in[3];
    const float* a1s  = (const float*)d_in[4];
    const float* a1d  = (const float*)d_in[5];
    const float* b1   = (const float*)d_in[6];
    const float* W2   = (const float*)d_in[7];
    const float* a2s  = (const float*)d_in[8];
    const float* a2d  = (const float*)d_in[9];
    const float* b2   = (const float*)d_in[10];
    const float* fc_w = (const float*)d_in[11];
    const float* fc_b = (const float*)d_in[12];
    float* out = (float*)d_out;

    char* p = (char*)d_ws;
    auto alloc = [&](size_t bytes) -> char* {
        char* r = p; p += (bytes + 255) & ~(size_t)255; return r;
    };
    int*   deg     = (int*)alloc((size_t)NN * 4);
    int*   fill    = (int*)alloc((size_t)NN * 4);
    float* pool    = (float*)alloc((size_t)NG * 64 * 4);
    float* cnt     = (float*)alloc((size_t)NG * 4);
    size_t zero_bytes = (size_t)(p - (char*)d_ws);
    int*   offs    = (int*)alloc((size_t)(NN + 1) * 4);
    int*   partials= (int*)alloc(64 * 4);
    int*   csr     = (int*)alloc((size_t)EP * 4);
    float* asrc    = (float*)alloc((size_t)NN * 4 * 4);
    float* adst    = (float*)alloc((size_t)NN * 4 * 4);
    ushort_t* hf2  = (ushort_t*)alloc((size_t)MPAD * HC * 2); // packed fp16 h
    f16*   xh      = (f16*)alloc((size_t)MPAD * F_IN * 2);
    f16*   act     = (f16*)alloc((size_t)MPAD * HC * 2);
    f16*   w1t     = (f16*)alloc((size_t)HC * F_IN * 2);      // [256][128]
    f16*   w2t     = (f16*)alloc((size_t)HC * HC * 2);        // [256][256]
    float* out2    = (float*)xh;   // alias: xh dead after gemm1

    hipMemsetAsync(d_ws, 0, zero_bytes, stream);

    // fused prep: edge hist + fp16 conversions (no batch histogram!)
    int prep_n = EP + XN4 + NW;
    prep_kernel<<<(prep_n + 255) / 256, 256, 0, stream>>>(
        ei + NE, x, W1, W2, deg, xh, w1t, w2t);
    scan_p1<<<49, 256, 0, stream>>>(deg, partials);
    scan_p3<<<49, 256, 0, stream>>>(deg, partials, offs);
    edge_fill<<<(EP + 255) / 256, 256, 0, stream>>>(ei, ei + NE, offs, fill, csr);

    dim3 gg((NN + 127) / 128, HC / 128);
    int nb4 = (NN + 3) / 4;

    // layer 1 (fp16 GEMM + fused alpha/packed-fp16-h epilogue)
    gemm_gat<<<gg, 256, 0, stream>>>(xh, w1t, a1s, a1d, hf2, asrc, adst, NN, F_IN);
    gat_agg<1><<<nb4, 256, 0, stream>>>(hf2, asrc, adst, offs, csr, b1, act, nullptr);
    // layer 2
    gemm_gat<<<gg, 256, 0, stream>>>(act, w2t, a2s, a2d, hf2, asrc, adst, NN, HC);
    gat_agg<0><<<nb4, 256, 0, stream>>>(hf2, asrc, adst, offs, csr, b2, nullptr, out2);
    // readout
    pool_kernel<<<((NN + 15) / 16 + 3) / 4, 256, 0, stream>>>(out2, batch, pool, cnt);
    fc_kernel<<<(NG * NOUT + 255) / 256, 256, 0, stream>>>(pool, cnt, fc_w, fc_b, out);
}

// Round 15
// 370.858 us; speedup vs baseline: 1.0457x; 1.0457x over previous
//
#include <hip/hip_runtime.h>
#include <hip/hip_bf16.h>
#include <cstddef>
#include <cstdint>

// Problem constants (from reference)
#define NN 50000
#define MPAD 50048      // 391 tiles * 128
#define F_IN 128
#define NH 4
#define NC 64
#define NE 800000
#define NG 128
#define NOUT 8
#define HC 256          // NH*NC
#define EP (NE + NN)    // edges + self loops

typedef unsigned short ushort_t;
typedef _Float16 f16;
typedef __attribute__((ext_vector_type(2))) _Float16 f16x2;
typedef __attribute__((ext_vector_type(8))) _Float16 f16x8;
typedef __attribute__((ext_vector_type(4))) float f32x4;

// ---------------------------------------------------------------------------
// helpers
// ---------------------------------------------------------------------------
__device__ __forceinline__ float lrelu02(float x) { return x > 0.0f ? x : 0.2f * x; }
__device__ __forceinline__ float elu1(float x)    { return x > 0.0f ? x : expm1f(x); }

__device__ __forceinline__ ushort_t f2h_bits(float f) {
    f16 h = (f16)f;
    union { f16 h; ushort_t u; } cv; cv.h = h;
    return cv.u;
}
__device__ __forceinline__ uint32_t pack2h(float a, float b) {
    union { f16 h[2]; uint32_t u; } cv;
    cv.h[0] = (f16)a; cv.h[1] = (f16)b;
    return cv.u;
}
__device__ __forceinline__ f16x2 as_h2(uint32_t q) {
    union { uint32_t u; f16x2 h; } cv; cv.u = q;
    return cv.h;
}
__device__ __forceinline__ void h2_unpack(uint32_t q, float& lo, float& hi) {
    union { uint32_t u; f16 h[2]; } cv; cv.u = q;
    lo = (float)cv.h[0];
    hi = (float)cv.h[1];
}

// async global -> LDS, 16B per lane; lds dest = wave-uniform base + lane*16
__device__ __forceinline__ void gld16(const void* g, void* l) {
    __builtin_amdgcn_global_load_lds(
        (const __attribute__((address_space(1))) unsigned int*)g,
        (__attribute__((address_space(3))) unsigned int*)l, 16, 0, 0);
}

// ---------------------------------------------------------------------------
// fused prep: edge histogram + x->fp16 + W->fp16^T
// (NO batch histogram — 50K same-line float atomics cost 187us in R8.)
// ---------------------------------------------------------------------------
#define XN4 (NN * F_IN / 4)
#define NW (F_IN * HC + HC * HC)
__global__ void prep_kernel(const int* __restrict__ edst,
                            const float* __restrict__ x,
                            const float* __restrict__ W1,
                            const float* __restrict__ W2,
                            int* __restrict__ deg,
                            f16* __restrict__ xh,
                            f16* __restrict__ w1t, f16* __restrict__ w2t) {
    int idx = blockIdx.x * blockDim.x + threadIdx.x;
    if (idx < EP) {
        int d = (idx < NE) ? edst[idx] : (idx - NE);
        atomicAdd(&deg[d], 1);
        return;
    }
    idx -= EP;
    if (idx < XN4) {
        float4 v = ((const float4*)x)[idx];
        f16 o[4] = {(f16)v.x, (f16)v.y, (f16)v.z, (f16)v.w};
        *(uint2*)(xh + idx * 4) = *(const uint2*)o;
        return;
    }
    idx -= XN4;
    const int n1 = F_IN * HC;
    if (idx < n1) {
        int k = idx / HC, n = idx % HC;
        w1t[n * F_IN + k] = (f16)W1[idx];
    } else if (idx < NW) {
        int i2 = idx - n1;
        int k = i2 / HC, n = i2 % HC;
        w2t[n * HC + k] = (f16)W2[i2];
    }
}

// ---------------------------------------------------------------------------
// CSR build: exclusive scan + fill (src ids, dst-sorted)
// ---------------------------------------------------------------------------
__global__ __launch_bounds__(256) void scan_p1(const int* __restrict__ deg,
                                               int* __restrict__ partials) {
    __shared__ int lds[256];
    int b = blockIdx.x, t = threadIdx.x;
    int i0 = b * 1024 + t * 4;
    int s = 0;
#pragma unroll
    for (int j = 0; j < 4; j++) { int i = i0 + j; if (i < NN) s += deg[i]; }
    lds[t] = s;
    __syncthreads();
    for (int o = 128; o; o >>= 1) { if (t < o) lds[t] += lds[t + o]; __syncthreads(); }
    if (t == 0) partials[b] = lds[0];
}

__global__ __launch_bounds__(256) void scan_p3(const int* __restrict__ deg,
                                               const int* __restrict__ partials,
                                               int* __restrict__ offs) {
    __shared__ int lds[256];
    __shared__ int base_s;
    int b = blockIdx.x, t = threadIdx.x;
    if (t == 0) {
        int s = 0;
        for (int i = 0; i < b; i++) s += partials[i];
        base_s = s;
        if (b == 0) offs[0] = 0;
    }
    int i0 = b * 1024 + t * 4;
    int v[4]; int s = 0;
#pragma unroll
    for (int j = 0; j < 4; j++) { int i = i0 + j; v[j] = (i < NN) ? deg[i] : 0; s += v[j]; }
    lds[t] = s;
    __syncthreads();
    for (int o = 1; o < 256; o <<= 1) {
        int x = (t >= o) ? lds[t - o] : 0;
        __syncthreads();
        lds[t] += x;
        __syncthreads();
    }
    int run = base_s + (lds[t] - s);
#pragma unroll
    for (int j = 0; j < 4; j++) { run += v[j]; int i = i0 + j; if (i < NN) offs[i + 1] = run; }
}

__global__ void edge_fill(const int* __restrict__ esrc, const int* __restrict__ edst,
                          const int* __restrict__ offs, int* __restrict__ fill,
                          int* __restrict__ csr) {
    int e = blockIdx.x * blockDim.x + threadIdx.x;
    if (e >= EP) return;
    int s, d;
    if (e < NE) { s = esrc[e]; d = edst[e]; } else { s = d = e - NE; }
    int pos = offs[d] + atomicAdd(&fill[d], 1);
    csr[pos] = s;
}

// ---------------------------------------------------------------------------
// fp16 MFMA GEMM, fused GAT epilogue (R10 shape, BK=32).
// C/D: col=lane&15, row=quad*4+reg. launch_bounds(256,3): 3 blocks/CU covers
// the per-iteration vmcnt(0) barrier drain (K-loop is only 4-8 iterations).
// hf2 dword layout [node][by*64+c]: dword = (hi: head 2by+1, lo: head 2by)
// packed fp16 for channel c (contiguous 256B/row per block).
// ---------------------------------------------------------------------------
__global__ __launch_bounds__(256, 3) void gemm_gat(
        const f16* __restrict__ A, const f16* __restrict__ BT,
        const float* __restrict__ a_s, const float* __restrict__ a_d,
        ushort_t* __restrict__ hf2, float* __restrict__ asrc,
        float* __restrict__ adst, int M, int K) {
    __shared__ alignas(16) char smem[33792];   // staging 16KB / repack 33.8KB
    f16* lA = (f16*)smem;            // [128 rows][32 k]
    f16* lB = (f16*)smem + 4096;     // [128 rows][32 k]

    int t = threadIdx.x;
    int wave = t >> 6, lane = t & 63;
    int wm = wave >> 1, wn = wave & 1;
    int quad = lane >> 4, l15 = lane & 15;
    int tileM = blockIdx.x * 128;
    int by = blockIdx.y;

    f32x4 acc[4][4];
#pragma unroll
    for (int f = 0; f < 4; f++)
#pragma unroll
        for (int g = 0; g < 4; g++) acc[f][g] = (f32x4){0.f, 0.f, 0.f, 0.f};

    for (int k0 = 0; k0 < K; k0 += 32) {
        __syncthreads();
#pragma unroll
        for (int i = 0; i < 2; i++) {
            int c = wave * 2 + i;
            int row = c * 16 + (lane >> 2);
            int kk = k0 + (lane & 3) * 8;
            gld16(A + (size_t)(tileM + row) * K + kk, &lA[c * 512]);
            gld16(BT + (size_t)(by * 128 + row) * K + kk, &lB[c * 512]);
        }
        __syncthreads();

        f16x8 ah[4], bh[4];
#pragma unroll
        for (int f = 0; f < 4; f++)
            ah[f] = *(const f16x8*)&lA[(wm * 64 + f * 16 + l15) * 32 + quad * 8];
#pragma unroll
        for (int g = 0; g < 4; g++)
            bh[g] = *(const f16x8*)&lB[(wn * 64 + g * 16 + l15) * 32 + quad * 8];
#pragma unroll
        for (int f = 0; f < 4; f++)
#pragma unroll
            for (int g = 0; g < 4; g++)
                acc[f][g] = __builtin_amdgcn_mfma_f32_16x16x32_f16(ah[f], bh[g], acc[f][g], 0, 0, 0);
    }

    // ---- epilogue 1: per-head attention dots (this wave's 64 cols = 1 head)
    int head = (by << 1) | wn;
    float as_v[4], ad_v[4];
#pragma unroll
    for (int g = 0; g < 4; g++) {
        as_v[g] = a_s[head * 64 + g * 16 + l15];
        ad_v[g] = a_d[head * 64 + g * 16 + l15];
    }
#pragma unroll
    for (int f = 0; f < 4; f++) {
#pragma unroll
        for (int r = 0; r < 4; r++) {
            float ps = acc[f][0][r] * as_v[0] + acc[f][1][r] * as_v[1]
                     + acc[f][2][r] * as_v[2] + acc[f][3][r] * as_v[3];
            float pd = acc[f][0][r] * ad_v[0] + acc[f][1][r] * ad_v[1]
                     + acc[f][2][r] * ad_v[2] + acc[f][3][r] * ad_v[3];
#pragma unroll
            for (int o = 1; o < 16; o <<= 1) {
                ps += __shfl_xor(ps, o);
                pd += __shfl_xor(pd, o);
            }
            int row = tileM + wm * 64 + f * 16 + quad * 4 + r;
            if (l15 == 0 && row < M) {
                asrc[row * 4 + head] = ps;
                adst[row * 4 + head] = pd;
            }
        }
    }

    // ---- epilogue 2: packed fp16 tile via padded LDS repack.
    // lC2 ushort layout: [128 rows][stride 132] ; ushort idx = c*2 + wn.
    __syncthreads();   // K-loop staging LDS dead
    ushort_t* lC2u = (ushort_t*)smem;
    const uint32_t* lC2d = (const uint32_t*)smem;
#pragma unroll
    for (int f = 0; f < 4; f++)
#pragma unroll
        for (int g = 0; g < 4; g++)
#pragma unroll
            for (int r = 0; r < 4; r++)
                lC2u[(wm * 64 + f * 16 + quad * 4 + r) * 132 + (g * 16 + l15) * 2 + wn] =
                    f2h_bits(acc[f][g][r]);
    __syncthreads();
    uint32_t* hb2 = (uint32_t*)hf2;
#pragma unroll
    for (int it = 0; it < 32; it++) {
        int row = wave * 32 + it;
        uint32_t v = lC2d[row * 66 + lane];
        hb2[(size_t)(tileM + row) * 128 + by * 64 + lane] = v;
    }
}

// ---------------------------------------------------------------------------
// GAT aggregation: one wave per node. Block = 4 waves = 4 nodes.
// deg<=64 fast path: plain softmax (logits 1/lane, 1 exp/head).
// Pass 2: manual 4-wide load batching with NAMED registers q0..q3 (static
// indices — arrays get demoted to LDS, named vars cannot be). Measured MLP
// curve: ~2 in flight (compiler default) = 86us, 4-wide = 73.4us (OPTIMUM),
// 8-wide = 80.3us (vmcnt-drain + occupancy loss). NT loads regress (R12).
// CONCAT=1: fp16 act out; CONCAT=0: shfl_xor(32) head-pair -> mean + bias.
// ---------------------------------------------------------------------------
template <int CONCAT>
__global__ __launch_bounds__(256) void gat_agg(const ushort_t* __restrict__ hf2,
                                               const float* __restrict__ asrc,
                                               const float* __restrict__ adst,
                                               const int* __restrict__ offs,
                                               const int* __restrict__ csr,
                                               const float* __restrict__ bias,
                                               f16* __restrict__ oh,
                                               float* __restrict__ of) {
    __shared__ uint2 lw[4][64];   // per-edge weights, packed (h_even,h_odd) fp16
    int wave = threadIdx.x >> 6, lane = threadIdx.x & 63;
    int node = blockIdx.x * 4 + wave;
    if (node >= NN) return;
    int start = offs[node];
    int deg = offs[node + 1] - start;
    float4 ad = *(const float4*)(adst + node * 4);

    float w0, w1, w2, w3;
    float m0, m1, m2, m3, i0, i1, i2, i3;
    int msrc = 0;

    if (deg <= 64) {
        // ---------- fast path: plain softmax, 1 exp/head ----------
        float t0 = -1e30f, t1 = -1e30f, t2 = -1e30f, t3 = -1e30f;
        if (lane < deg) {
            int sidx = csr[start + lane];
            float4 as = *(const float4*)(asrc + sidx * 4);
            t0 = lrelu02(as.x + ad.x);
            t1 = lrelu02(as.y + ad.y);
            t2 = lrelu02(as.z + ad.z);
            t3 = lrelu02(as.w + ad.w);
            msrc = sidx;
        }
        m0 = t0; m1 = t1; m2 = t2; m3 = t3;
#pragma unroll
        for (int o = 1; o < 64; o <<= 1) {
            m0 = fmaxf(m0, __shfl_xor(m0, o));
            m1 = fmaxf(m1, __shfl_xor(m1, o));
            m2 = fmaxf(m2, __shfl_xor(m2, o));
            m3 = fmaxf(m3, __shfl_xor(m3, o));
        }
        w0 = __expf(t0 - m0);
        w1 = __expf(t1 - m1);
        w2 = __expf(t2 - m2);
        w3 = __expf(t3 - m3);
        float s0 = w0, s1 = w1, s2 = w2, s3 = w3;
#pragma unroll
        for (int o = 1; o < 64; o <<= 1) {
            s0 += __shfl_xor(s0, o);
            s1 += __shfl_xor(s1, o);
            s2 += __shfl_xor(s2, o);
            s3 += __shfl_xor(s3, o);
        }
        i0 = 1.0f / (s0 + 1e-16f);
        i1 = 1.0f / (s1 + 1e-16f);
        i2 = 1.0f / (s2 + 1e-16f);
        i3 = 1.0f / (s3 + 1e-16f);
        w0 *= i0; w1 *= i1; w2 *= i2; w3 *= i3;
    } else {
        // ---------- slow path (deg>64; not hit for this input) ----------
        m0 = m1 = m2 = m3 = -1e30f;
        float s0 = 0.f, s1 = 0.f, s2 = 0.f, s3 = 0.f;
        float e0 = 0.f, e1 = 0.f, e2 = 0.f, e3 = 0.f;
        for (int j = lane; j < deg; j += 64) {
            int sidx = csr[start + j];
            float4 as = *(const float4*)(asrc + sidx * 4);
            float t0 = lrelu02(as.x + ad.x);
            float t1 = lrelu02(as.y + ad.y);
            float t2 = lrelu02(as.z + ad.z);
            float t3 = lrelu02(as.w + ad.w);
            if (j == lane) { e0 = t0; e1 = t1; e2 = t2; e3 = t3; msrc = sidx; }
            float nm;
            nm = fmaxf(m0, t0); s0 = s0 * __expf(m0 - nm) + __expf(t0 - nm); m0 = nm;
            nm = fmaxf(m1, t1); s1 = s1 * __expf(m1 - nm) + __expf(t1 - nm); m1 = nm;
            nm = fmaxf(m2, t2); s2 = s2 * __expf(m2 - nm) + __expf(t2 - nm); m2 = nm;
            nm = fmaxf(m3, t3); s3 = s3 * __expf(m3 - nm) + __expf(t3 - nm); m3 = nm;
        }
        for (int o = 32; o; o >>= 1) {
            float om, os, nm;
            om = __shfl_xor(m0, o); os = __shfl_xor(s0, o);
            nm = fmaxf(m0, om); s0 = s0 * __expf(m0 - nm) + os * __expf(om - nm); m0 = nm;
            om = __shfl_xor(m1, o); os = __shfl_xor(s1, o);
            nm = fmaxf(m1, om); s1 = s1 * __expf(m1 - nm) + os * __expf(om - nm); m1 = nm;
            om = __shfl_xor(m2, o); os = __shfl_xor(s2, o);
            nm = fmaxf(m2, om); s2 = s2 * __expf(m2 - nm) + os * __expf(om - nm); m2 = nm;
            om = __shfl_xor(m3, o); os = __shfl_xor(s3, o);
            nm = fmaxf(m3, om); s3 = s3 * __expf(m3 - nm) + os * __expf(om - nm); m3 = nm;
        }
        i0 = 1.0f / (s0 + 1e-16f);
        i1 = 1.0f / (s1 + 1e-16f);
        i2 = 1.0f / (s2 + 1e-16f);
        i3 = 1.0f / (s3 + 1e-16f);
        w0 = __expf(e0 - m0) * i0;
        w1 = __expf(e1 - m1) * i1;
        w2 = __expf(e2 - m2) * i2;
        w3 = __expf(e3 - m3) * i3;
    }

    // park weights in LDS, packed fp16 (wave-private; no barrier needed):
    // dword 0 = (w_head0, w_head1), dword 1 = (w_head2, w_head3)
    lw[wave][lane] = (uint2){pack2h(w0, w1), pack2h(w2, w3)};

    // gather: lane l -> head pair hp=l>>5, channels c0=2*(l&31), c0+1
    int hp = lane >> 5;
    const uint32_t* lwu = (const uint32_t*)&lw[wave][0];  // [64][2] dword view
    float aE0 = 0.f, aO0 = 0.f, aE1 = 0.f, aO1 = 0.f; // (even/odd head) x (c0/c1)
    const uint32_t* hb = (const uint32_t*)hf2 + lane * 2;
    int jmax = deg < 64 ? deg : 64;

    int j = 0;
    for (; j + 4 <= jmax; j += 4) {
        int s0 = __builtin_amdgcn_readlane(msrc, j);
        int s1 = __builtin_amdgcn_readlane(msrc, j + 1);
        int s2 = __builtin_amdgcn_readlane(msrc, j + 2);
        int s3 = __builtin_amdgcn_readlane(msrc, j + 3);
        uint2 q0 = *(const uint2*)(hb + (size_t)s0 * 128);
        uint2 q1 = *(const uint2*)(hb + (size_t)s1 * 128);
        uint2 q2 = *(const uint2*)(hb + (size_t)s2 * 128);
        uint2 q3 = *(const uint2*)(hb + (size_t)s3 * 128);
        f16x2 wA = as_h2(lwu[(j + 0) * 2 + hp]);
        f16x2 wB = as_h2(lwu[(j + 1) * 2 + hp]);
        f16x2 wC = as_h2(lwu[(j + 2) * 2 + hp]);
        f16x2 wD = as_h2(lwu[(j + 3) * 2 + hp]);
        f16x2 x0 = as_h2(q0.x), y0 = as_h2(q0.y);
        f16x2 x1 = as_h2(q1.x), y1 = as_h2(q1.y);
        f16x2 x2 = as_h2(q2.x), y2 = as_h2(q2.y);
        f16x2 x3 = as_h2(q3.x), y3 = as_h2(q3.y);
        aE0 += (float)x0[0] * (float)wA[0]; aO0 += (float)x0[1] * (float)wA[1];
        aE1 += (float)y0[0] * (float)wA[0]; aO1 += (float)y0[1] * (float)wA[1];
        aE0 += (float)x1[0] * (float)wB[0]; aO0 += (float)x1[1] * (float)wB[1];
        aE1 += (float)y1[0] * (float)wB[0]; aO1 += (float)y1[1] * (float)wB[1];
        aE0 += (float)x2[0] * (float)wC[0]; aO0 += (float)x2[1] * (float)wC[1];
        aE1 += (float)y2[0] * (float)wC[0]; aO1 += (float)y2[1] * (float)wC[1];
        aE0 += (float)x3[0] * (float)wD[0]; aO0 += (float)x3[1] * (float)wD[1];
        aE1 += (float)y3[0] * (float)wD[0]; aO1 += (float)y3[1] * (float)wD[1];
    }
    for (; j < jmax; j++) {
        int sidx = __builtin_amdgcn_readlane(msrc, j);
        f16x2 wh = as_h2(lwu[j * 2 + hp]);
        uint2 q = *(const uint2*)(hb + (size_t)sidx * 128);
        f16x2 qx = as_h2(q.x), qy = as_h2(q.y);
        aE0 += (float)qx[0] * (float)wh[0];
        aO0 += (float)qx[1] * (float)wh[1];
        aE1 += (float)qy[0] * (float)wh[0];
        aO1 += (float)qy[1] * (float)wh[1];
    }
    for (int jj = 64; jj < deg; jj++) {  // correctness fallback (deg>64); not hit
        int sidx = csr[start + jj];
        float4 as = *(const float4*)(asrc + sidx * 4);
        float u0 = __expf(lrelu02(as.x + ad.x) - m0) * i0;
        float u1 = __expf(lrelu02(as.y + ad.y) - m1) * i1;
        float u2 = __expf(lrelu02(as.z + ad.z) - m2) * i2;
        float u3 = __expf(lrelu02(as.w + ad.w) - m3) * i3;
        float ue = hp ? u2 : u0;
        float uo = hp ? u3 : u1;
        uint2 q = *(const uint2*)(hb + (size_t)sidx * 128);
        float xl, xh2, yl, yh;
        h2_unpack(q.x, xl, xh2);
        h2_unpack(q.y, yl, yh);
        aE0 += ue * xl;
        aO0 += uo * xh2;
        aE1 += ue * yl;
        aO1 += uo * yh;
    }

    int c0 = (lane & 31) * 2;
    int he = hp * 2, ho = hp * 2 + 1;
    if (CONCAT) {
        size_t base = (size_t)node * HC;
        float vE0 = elu1(aE0 + bias[he * 64 + c0]);
        float vE1 = elu1(aE1 + bias[he * 64 + c0 + 1]);
        float vO0 = elu1(aO0 + bias[ho * 64 + c0]);
        float vO1 = elu1(aO1 + bias[ho * 64 + c0 + 1]);
        f16 pe[2] = {(f16)vE0, (f16)vE1};
        f16 po[2] = {(f16)vO0, (f16)vO1};
        *(uint32_t*)(oh + base + he * 64 + c0) = *(const uint32_t*)pe;
        *(uint32_t*)(oh + base + ho * 64 + c0) = *(const uint32_t*)po;
    } else {
        float s0 = aE0 + aO0;     // pair-sum, channel c0
        float s1 = aE1 + aO1;     // pair-sum, channel c0+1
        s0 += __shfl_xor(s0, 32); // + other head pair
        s1 += __shfl_xor(s1, 32);
        if (hp == 0) {
            float2 v = {0.25f * s0 + bias[c0], 0.25f * s1 + bias[c0 + 1]};
            *(float2*)(of + (size_t)node * NC + c0) = v;
        }
    }
}

// ---------------------------------------------------------------------------
// global mean pool (batch sorted): run-length accumulate 16 nodes/wave,
// one atomic per (graph-run, wave) — FEW spread atomics, not a histogram.
// ---------------------------------------------------------------------------
__global__ __launch_bounds__(256) void pool_kernel(const float* __restrict__ out2,
                                                   const int* __restrict__ batch,
                                                   float* __restrict__ pool,
                                                   float* __restrict__ cnt) {
    int gw = (blockIdx.x * blockDim.x + threadIdx.x) >> 6;
    int lane = threadIdx.x & 63;
    int start = gw * 16;
    if (start >= NN) return;
    int end = start + 16 < NN ? start + 16 : NN;
    int curg = batch[start];
    float acc = 0.f; int run = 0;
    for (int node = start; node < end; node++) {
        int g = batch[node];
        if (g != curg) {
            atomicAdd(&pool[curg * 64 + lane], acc);
            if (lane == 0) atomicAdd(&cnt[curg], (float)run);
            curg = g; acc = 0.f; run = 0;
        }
        acc += out2[(size_t)node * NC + lane];
        run++;
    }
    atomicAdd(&pool[curg * 64 + lane], acc);
    if (lane == 0) atomicAdd(&cnt[curg], (float)run);
}

__global__ void fc_kernel(const float* __restrict__ pool, const float* __restrict__ cnt,
                          const float* __restrict__ fc_w, const float* __restrict__ fc_b,
                          float* __restrict__ out) {
    int idx = blockIdx.x * blockDim.x + threadIdx.x;
    if (idx >= NG * NOUT) return;
    int g = idx >> 3, o = idx & 7;
    float inv = 1.0f / fmaxf(cnt[g], 1.0f);
    float s = 0.f;
#pragma unroll
    for (int c = 0; c < 64; c++) s += pool[g * 64 + c] * fc_w[c * 8 + o];
    out[idx] = s * inv + fc_b[o];
}

// ---------------------------------------------------------------------------
extern "C" void kernel_launch(void* const* d_in, const int* in_sizes, int n_in,
                              void* d_out, int out_size, void* d_ws, size_t ws_size,
                              hipStream_t stream) {
    const float* x    = (const float*)d_in[0];
    const int*   ei   = (const int*)d_in[1];   // [2, E]
    const int*   batch= (const int*)d_in[2];
    const float* W1   = (const float*)d_in[3];
    const float* a1s  = (const float*)d_in[4];
    const float* a1d  = (const float*)d_in[5];
    const float* b1   = (const float*)d_in[6];
    const float* W2   = (const float*)d_in[7];
    const float* a2s  = (const float*)d_in[8];
    const float* a2d  = (const float*)d_in[9];
    const float* b2   = (const float*)d_in[10];
    const float* fc_w = (const float*)d_in[11];
    const float* fc_b = (const float*)d_in[12];
    float* out = (float*)d_out;

    char* p = (char*)d_ws;
    auto alloc = [&](size_t bytes) -> char* {
        char* r = p; p += (bytes + 255) & ~(size_t)255; return r;
    };
    int*   deg     = (int*)alloc((size_t)NN * 4);
    int*   fill    = (int*)alloc((size_t)NN * 4);
    float* pool    = (float*)alloc((size_t)NG * 64 * 4);
    float* cnt     = (float*)alloc((size_t)NG * 4);
    size_t zero_bytes = (size_t)(p - (char*)d_ws);
    int*   offs    = (int*)alloc((size_t)(NN + 1) * 4);
    int*   partials= (int*)alloc(64 * 4);
    int*   csr     = (int*)alloc((size_t)EP * 4);
    float* asrc    = (float*)alloc((size_t)NN * 4 * 4);
    float* adst    = (float*)alloc((size_t)NN * 4 * 4);
    ushort_t* hf2  = (ushort_t*)alloc((size_t)MPAD * HC * 2); // packed fp16 h
    f16*   xh      = (f16*)alloc((size_t)MPAD * F_IN * 2);
    f16*   act     = (f16*)alloc((size_t)MPAD * HC * 2);
    f16*   w1t     = (f16*)alloc((size_t)HC * F_IN * 2);      // [256][128]
    f16*   w2t     = (f16*)alloc((size_t)HC * HC * 2);        // [256][256]
    float* out2    = (float*)xh;   // alias: xh dead after gemm1

    hipMemsetAsync(d_ws, 0, zero_bytes, stream);

    // fused prep: edge hist + fp16 conversions (no batch histogram!)
    int prep_n = EP + XN4 + NW;
    prep_kernel<<<(prep_n + 255) / 256, 256, 0, stream>>>(
        ei + NE, x, W1, W2, deg, xh, w1t, w2t);
    scan_p1<<<49, 256, 0, stream>>>(deg, partials);
    scan_p3<<<49, 256, 0, stream>>>(deg, partials, offs);
    edge_fill<<<(EP + 255) / 256, 256, 0, stream>>>(ei, ei + NE, offs, fill, csr);

    dim3 gg((NN + 127) / 128, HC / 128);
    int nb4 = (NN + 3) / 4;

    // layer 1 (fp16 GEMM + fused alpha/packed-fp16-h epilogue)
    gemm_gat<<<gg, 256, 0, stream>>>(xh, w1t, a1s, a1d, hf2, asrc, adst, NN, F_IN);
    gat_agg<1><<<nb4, 256, 0, stream>>>(hf2, asrc, adst, offs, csr, b1, act, nullptr);
    // layer 2
    gemm_gat<<<gg, 256, 0, stream>>>(act, w2t, a2s, a2d, hf2, asrc, adst, NN, HC);
    gat_agg<0><<<nb4, 256, 0, stream>>>(hf2, asrc, adst, offs, csr, b2, nullptr, out2);
    // readout
    pool_kernel<<<((NN + 15) / 16 + 3) / 4, 256, 0, stream>>>(out2, batch, pool, cnt);
    fc_kernel<<<(NG * NOUT + 255) / 256, 256, 0, stream>>>(pool, cnt, fc_w, fc_b, out);
}